// Round 1
// baseline (206.530 us; speedup 1.0000x reference)
//
#include <hip/hip_runtime.h>
#include <hip/hip_bf16.h>
#include <math.h>

#ifndef PI_F
#define PI_F 3.14159265358979323846f
#endif

// out[i] = (-pi^2 - (P*pi)^2 + a^2) * sin(pi*x0) * sin(P*pi*x1), P=1
// N = 16777216 rows, input [N,2] f32 interleaved, output [N,1] f32.
// Memory-bound: 192 MiB traffic -> ~30us floor at 6.3 TB/s.
// 4 rows per thread: 2x float4 loads (x0,x1 pairs) + 1x float4 store.

__global__ __launch_bounds__(256) void helm_kernel(
    const float4* __restrict__ in,   // N/2 float4s (each = 2 rows)
    const float* __restrict__ a,
    float4* __restrict__ out,        // N/4 float4s
    int n_quads)                     // N/4
{
    int i = blockIdx.x * blockDim.x + threadIdx.x;
    if (i >= n_quads) return;

    float av = a[0];
    float coef = av * av - 2.0f * (PI_F * PI_F);  // -pi^2 - pi^2 + a^2

    float4 v0 = in[2 * i];       // rows 4i, 4i+1
    float4 v1 = in[2 * i + 1];   // rows 4i+2, 4i+3

    float4 o;
    o.x = coef * __sinf(PI_F * v0.x) * __sinf(PI_F * v0.y);
    o.y = coef * __sinf(PI_F * v0.z) * __sinf(PI_F * v0.w);
    o.z = coef * __sinf(PI_F * v1.x) * __sinf(PI_F * v1.y);
    o.w = coef * __sinf(PI_F * v1.z) * __sinf(PI_F * v1.w);

    out[i] = o;
}

extern "C" void kernel_launch(void* const* d_in, const int* in_sizes, int n_in,
                              void* d_out, int out_size, void* d_ws, size_t ws_size,
                              hipStream_t stream) {
    const float4* in = (const float4*)d_in[0];
    const float* a = (const float*)d_in[1];
    float4* out = (float4*)d_out;

    int n = out_size;            // 16777216 rows
    int n_quads = n / 4;         // 4194304 threads

    dim3 block(256);
    dim3 grid((n_quads + 255) / 256);
    helm_kernel<<<grid, block, 0, stream>>>(in, a, out, n_quads);
}

// Round 2
// 199.177 us; speedup vs baseline: 1.0369x; 1.0369x over previous
//
#include <hip/hip_runtime.h>
#include <hip/hip_bf16.h>
#include <math.h>

#ifndef PI_F
#define PI_F 3.14159265358979323846f
#endif

// out[i] = (-pi^2 - (P*pi)^2 + a^2) * sin(pi*x0) * sin(P*pi*x1), P=1
// N = 16777216 rows, input [N,2] f32 interleaved, output [N,1] f32.
// Memory-bound: 192 MiB traffic -> ~30us floor at 6.3 TB/s.
//
// Layout: 2 rows per thread. One lane-contiguous float4 load (16 B/lane,
// the m13-verified 6.29 TB/s pattern) + one lane-contiguous float2 store.
// Nontemporal hints: pure streaming, no reuse -> don't allocate in cache.

typedef float vf4 __attribute__((ext_vector_type(4)));
typedef float vf2 __attribute__((ext_vector_type(2)));

__global__ __launch_bounds__(256) void helm_kernel(
    const vf4* __restrict__ in,   // N/2 float4s (each = 2 rows)
    const float* __restrict__ a,
    vf2* __restrict__ out,        // N/2 float2s
    int n4)                       // N/2
{
    int i = blockIdx.x * blockDim.x + threadIdx.x;
    if (i >= n4) return;

    float av = a[0];
    float coef = av * av - 2.0f * (PI_F * PI_F);  // -pi^2 - pi^2 + a^2

    vf4 v = __builtin_nontemporal_load(&in[i]);

    vf2 o;
    o.x = coef * __sinf(PI_F * v.x) * __sinf(PI_F * v.y);
    o.y = coef * __sinf(PI_F * v.z) * __sinf(PI_F * v.w);

    __builtin_nontemporal_store(o, &out[i]);
}

extern "C" void kernel_launch(void* const* d_in, const int* in_sizes, int n_in,
                              void* d_out, int out_size, void* d_ws, size_t ws_size,
                              hipStream_t stream) {
    const vf4* in = (const vf4*)d_in[0];
    const float* a = (const float*)d_in[1];
    vf2* out = (vf2*)d_out;

    int n4 = out_size / 2;       // 8388608 threads, 2 rows each

    dim3 block(256);
    dim3 grid((n4 + 255) / 256);
    helm_kernel<<<grid, block, 0, stream>>>(in, a, out, n4);
}

// Round 3
// 198.608 us; speedup vs baseline: 1.0399x; 1.0029x over previous
//
#include <hip/hip_runtime.h>
#include <hip/hip_bf16.h>
#include <math.h>

#ifndef PI_F
#define PI_F 3.14159265358979323846f
#endif

// out[i] = (-pi^2 - (P*pi)^2 + a^2) * sin(pi*x0) * sin(P*pi*x1), P=1
// N = 16777216 rows, input [N,2] f32 interleaved, output [N,1] f32.
// Memory-bound: 192 MiB traffic -> ~30us floor at ~6.5 TB/s (fills hit 6.7).
//
// UNROLL=4 block-stride: each thread issues 4 independent lane-contiguous
// float4 loads back-to-back (4 KB/wave in flight) before any use -> MLP,
// then 4 sin-pairs, 4 lane-contiguous float2 stores. Nontemporal both ways
// (pure streaming, zero reuse).

typedef float vf4 __attribute__((ext_vector_type(4)));
typedef float vf2 __attribute__((ext_vector_type(2)));

#define UNROLL 4
#define BLOCK 256

__global__ __launch_bounds__(BLOCK) void helm_kernel(
    const vf4* __restrict__ in,   // N/2 float4s (each = 2 rows)
    const float* __restrict__ a,
    vf2* __restrict__ out,        // N/2 float2s
    int n4)                       // N/2
{
    const int tid = threadIdx.x;
    const int base = blockIdx.x * (BLOCK * UNROLL) + tid;

    float av = a[0];
    float coef = av * av - 2.0f * (PI_F * PI_F);  // -pi^2 - pi^2 + a^2

    if (base + (UNROLL - 1) * BLOCK < n4) {
        // fast path: all 4 in range (block-uniform branch)
        vf4 v[UNROLL];
#pragma unroll
        for (int k = 0; k < UNROLL; ++k)
            v[k] = __builtin_nontemporal_load(&in[base + k * BLOCK]);

#pragma unroll
        for (int k = 0; k < UNROLL; ++k) {
            vf2 o;
            o.x = coef * __sinf(PI_F * v[k].x) * __sinf(PI_F * v[k].y);
            o.y = coef * __sinf(PI_F * v[k].z) * __sinf(PI_F * v[k].w);
            __builtin_nontemporal_store(o, &out[base + k * BLOCK]);
        }
    } else {
#pragma unroll
        for (int k = 0; k < UNROLL; ++k) {
            int idx = base + k * BLOCK;
            if (idx < n4) {
                vf4 v = __builtin_nontemporal_load(&in[idx]);
                vf2 o;
                o.x = coef * __sinf(PI_F * v.x) * __sinf(PI_F * v.y);
                o.y = coef * __sinf(PI_F * v.z) * __sinf(PI_F * v.w);
                __builtin_nontemporal_store(o, &out[idx]);
            }
        }
    }
}

extern "C" void kernel_launch(void* const* d_in, const int* in_sizes, int n_in,
                              void* d_out, int out_size, void* d_ws, size_t ws_size,
                              hipStream_t stream) {
    const vf4* in = (const vf4*)d_in[0];
    const float* a = (const float*)d_in[1];
    vf2* out = (vf2*)d_out;

    int n4 = out_size / 2;                       // 8388608 float4s
    int per_block = BLOCK * UNROLL;              // 1024
    int grid = (n4 + per_block - 1) / per_block; // 8192

    helm_kernel<<<grid, BLOCK, 0, stream>>>(in, a, out, n4);
}